// Round 13
// baseline (87.126 us; speedup 1.0000x reference)
//
#include <hip/hip_runtime.h>
#include <hip/hip_bf16.h>

// Problem: B=16, T=8192, M=P=128, N2=128. Chunks: L=128, 64/batch, 1024 total.
// R13: split path (R12) + quarter-pipelined k3a staging + LDS-transposed coalesced
// y stores in k3b + merged k0. Fallback to R4 k1/k3 pair if ws can't hold bus.
#define LCH 128
#define NCH 64
#define NCHUNKS 1024

typedef __attribute__((ext_vector_type(8))) short short8v;
typedef __attribute__((ext_vector_type(4))) short short4v;
typedef __attribute__((ext_vector_type(4))) float f32x4;

// ws layout: float2 region, packs, then bus.
#define W2_LDINV 0          // [128 r][128 n]  Ld^{-(r+1)}   (float2 idx)
#define W2_LDP   16384      // [128 r][128 n]  Ld^{r+1}
#define W2_E     32768      // [1024 g][128 n]
#define W2_CIN   163840     // [1024 g][128 n]
#define WS_WPACK_BYTE  2359296              // 32768 bf16: [ntile16][ks4][lane64][j8]
#define WS_CCPACK_BYTE (2359296 + 65536)    // 32768 bf16: [ptile8][ks8][lane64][j8]
#define WS_BUS_BYTE    (2359296 + 131072)   // 1024 chunks x 64 KB bf16 bus
#define WS_NEED ((size_t)WS_BUS_BYTE + (size_t)NCHUNKS * 65536)

// bus layout (LDS and global, byte-identical): byte(s,n') = (s>>3)*4096 + n'*16 + (s&7)*2
#define BUS_BYTE(s, np) ((((s) >> 3) * 4096) + ((np) * 16) + (((s) & 7) * 2))

__device__ inline unsigned short f2bf(float f) {
    union { __hip_bfloat16 h; unsigned short u; } v;
    v.h = __float2bfloat16(f);
    return v.u;
}
__device__ inline short4v pack4(float a, float b, float c, float d) {
    union { __hip_bfloat162 h2[2]; short4v s4; } pk;
    pk.h2[0] = __float22bfloat162_rn(make_float2(a, b));
    pk.h2[1] = __float22bfloat162_rn(make_float2(c, d));
    return pk.s4;
}

// ---------------- k0: all setup in one launch (256 blocks x 512) ----------------
// blocks 0..127: power tables row r (f64 exact); 128..191: wpack; 192..255: ccpack.
__global__ void k0_all(const float* __restrict__ lp, const float* __restrict__ bp,
                       const float* __restrict__ cp, const float* __restrict__ delta,
                       float2* __restrict__ ws2, unsigned short* __restrict__ wpack,
                       unsigned short* __restrict__ ccpack) {
    const int r = blockIdx.x;
    const int tid = threadIdx.x;
    if (r < 128) {
        if (tid < 256) {
            const int n = tid & 127;
            const double d = (double)delta[0];
            const double lre = -exp((double)lp[n]);
            const double lim = (double)lp[128 + n];
            const double kk = (double)(r + 1) * d;
            if (tid < 128) {
                const double mag = exp(-lre * kk);
                ws2[W2_LDINV + r * 128 + n] = make_float2((float)(mag * cos(lim * kk)),
                                                          (float)(-mag * sin(lim * kk)));
            } else {
                const double mag = exp(lre * kk);
                ws2[W2_LDP + r * 128 + n] = make_float2((float)(mag * cos(lim * kk)),
                                                        (float)(mag * sin(lim * kk)));
            }
        }
    } else if (r < 192) {
        const int gid = (r - 128) * 512 + tid;         // 0..32767
        const int j = gid & 7;
        const int lane = (gid >> 3) & 63;
        const int ks = (gid >> 9) & 3;
        const int ntile = gid >> 11;
        const int np = ntile * 16 + (lane & 15);
        const int m = ks * 32 + ((lane >> 4) & 3) * 8 + j;
        const int n = np & 127;
        const double d = (double)delta[0];
        const double lre = -exp((double)lp[n]);
        const double lim = (double)lp[128 + n];
        const double er = exp(lre * d);
        const double ldr = er * cos(lim * d), ldi = er * sin(lim * d);
        const double nr = ldr - 1.0, ni = ldi;
        const double den = lre * lre + lim * lim;
        const double cr = (nr * lre + ni * lim) / den;
        const double ci = (ni * lre - nr * lim) / den;
        const double br = (double)bp[n * 128 + m];
        const double bi = (double)bp[16384 + n * 128 + m];
        const double v = (np < 128) ? (cr * br - ci * bi) : (cr * bi + ci * br);
        wpack[gid] = f2bf((float)v);
    } else {
        const int gid = (r - 192) * 512 + tid;         // 0..32767
        const int j = gid & 7;
        const int lane = (gid >> 3) & 63;
        const int ks = (gid >> 9) & 7;
        const int ptile = gid >> 12;
        const int p = ptile * 16 + (lane & 15);
        const int k = ks * 32 + ((lane >> 4) & 3) * 8 + j;
        const int n = k >> 1;
        const float v = ((k & 1) == 0) ? 2.0f * cp[p * 128 + n]
                                       : -2.0f * cp[16384 + p * 128 + n];
        ccpack[gid] = f2bf(v);
    }
}

// ---------------- shared helper: stage u chunk -> LDS bf16 [t][m], XOR swizzle ----------------
__device__ inline void stage_u(const float* __restrict__ uchunk, unsigned short* lds_u) {
    const float4* uf = (const float4*)uchunk;
    const int tid = threadIdx.x;
#pragma unroll
    for (int it = 0; it < 8; ++it) {
        const int f4 = it * 512 + tid;
        const float4 v = uf[f4];
        const int t = f4 >> 5;
        const int m = (f4 & 31) * 4;
        const int byte = (t * 256 + m * 2) ^ ((t & 7) << 4);
        *(short4v*)((char*)lds_u + byte) = pack4(v.x, v.y, v.z, v.w);
    }
}

// ================= k3a: quarter-pipelined stage -> GEMM1 -> scale -> bus + E =================
// Quarter q = u rows [32q, 32q+32): stage from prefetch regs, issue q+1 loads, barrier,
// GEMM1-q (acc[2][2]=16 AGPR) + Ldinv scale + bus store. Load latency hides under GEMM1.
__global__ __launch_bounds__(512, 6) void k3a_bus(const float* __restrict__ u,
                                                  float2* __restrict__ ws2,
                                                  const unsigned short* __restrict__ wpack,
                                                  char* __restrict__ busg) {
    __shared__ unsigned short lds_u[16384];   // 32 KB
    const int tid = threadIdx.x;
    const int lane = tid & 63;
    const int w = tid >> 6;
    const int tl = lane & 15;
    const int gq = (lane >> 4) & 3;
    const int g = blockIdx.x;
    const int b = g >> 6;
    const int c = g & 63;
    const int n = w * 16 + tl;
    char* busc = busg + (size_t)g * 65536;
    const float4* uf = (const float4*)(u + (size_t)(b * 8192 + c * 128) * 128);

    float4 pre0 = uf[tid];
    float4 pre1 = uf[512 + tid];
    float er = 0.f, ei = 0.f;

#pragma unroll
    for (int q = 0; q < 4; ++q) {
        // stage quarter q (rows 32q..32q+32) from prefetch regs
        {
            const int f0 = q * 1024 + tid;
            const int t0 = f0 >> 5, m0 = (f0 & 31) * 4;
            *(short4v*)((char*)lds_u + ((t0 * 256 + m0 * 2) ^ ((t0 & 7) << 4))) =
                pack4(pre0.x, pre0.y, pre0.z, pre0.w);
            const int f1 = q * 1024 + 512 + tid;
            const int t1 = f1 >> 5, m1 = (f1 & 31) * 4;
            *(short4v*)((char*)lds_u + ((t1 * 256 + m1 * 2) ^ ((t1 & 7) << 4))) =
                pack4(pre1.x, pre1.y, pre1.z, pre1.w);
        }
        if (q < 3) {    // issue next quarter's loads; latency hides under GEMM1 below
            pre0 = uf[(q + 1) * 1024 + tid];
            pre1 = uf[(q + 1) * 1024 + 512 + tid];
        }
        __builtin_amdgcn_sched_barrier(0);   // pin load issue into this quarter's slot
        __syncthreads();                     // quarter q visible to all waves

        // GEMM1 quarter q — launder wpack pointer so frag loads can't CSE across quarters
        unsigned long long wpu = (unsigned long long)wpack;
        asm volatile("" : "+s"(wpu));
        const short8v* wpq = (const short8v*)wpu;
        f32x4 acc[2][2];
        acc[0][0] = (f32x4)0.f; acc[0][1] = (f32x4)0.f;
        acc[1][0] = (f32x4)0.f; acc[1][1] = (f32x4)0.f;
        __builtin_amdgcn_s_setprio(1);
#pragma unroll
        for (int ks = 0; ks < 4; ++ks) {
            const short8v b0 = wpq[(w * 4 + ks) * 64 + lane];
            const short8v b1 = wpq[((8 + w) * 4 + ks) * 64 + lane];
#pragma unroll
            for (int tt2 = 0; tt2 < 2; ++tt2) {
                const int t = (q * 2 + tt2) * 16 + tl;
                const int byte = (t * 256 + (ks * 32 + gq * 8) * 2) ^ ((t & 7) << 4);
                const short8v a = *(const short8v*)((const char*)lds_u + byte);
                acc[tt2][0] = __builtin_amdgcn_mfma_f32_16x16x32_bf16(a, b0, acc[tt2][0], 0, 0, 0);
                acc[tt2][1] = __builtin_amdgcn_mfma_f32_16x16x32_bf16(a, b1, acc[tt2][1], 0, 0, 0);
            }
        }
        __builtin_amdgcn_s_setprio(0);
        __builtin_amdgcn_sched_barrier(0);

        // Ldinv scale + bus global store + E accumulation
#pragma unroll
        for (int tt2 = 0; tt2 < 2; ++tt2) {
            float vr[4], vi[4];
#pragma unroll
            for (int reg = 0; reg < 4; ++reg) {
                const int rr = (q * 2 + tt2) * 16 + gq * 4 + reg;
                const float2 li = ws2[W2_LDINV + rr * 128 + n];
                const float br = acc[tt2][0][reg], bi = acc[tt2][1][reg];
                vr[reg] = li.x * br - li.y * bi;
                vi[reg] = li.x * bi + li.y * br;
                er += vr[reg];
                ei += vi[reg];
            }
            const int s0 = (q * 2 + tt2) * 16 + gq * 4;
            const int rowr = w * 16 + tl;
            const int rowi = 128 + rowr;
            *(short4v*)(busc + BUS_BYTE(s0, rowr)) = pack4(vr[0], vr[1], vr[2], vr[3]);
            *(short4v*)(busc + BUS_BYTE(s0, rowi)) = pack4(vi[0], vi[1], vi[2], vi[3]);
        }
        __builtin_amdgcn_sched_barrier(0);
    }
    // E[g][n] = Ld^128 * sum_s (Ldinv[s] (.) Bu[s,n])
    er += __shfl_xor(er, 16); ei += __shfl_xor(ei, 16);
    er += __shfl_xor(er, 32); ei += __shfl_xor(ei, 32);
    const float2 ld = ws2[W2_LDP + 127 * 128 + n];
    if (lane < 16) {
        ws2[W2_E + g * 128 + n] = make_float2(ld.x * er - ld.y * ei,
                                              ld.x * ei + ld.y * er);
    }
}

// ---------------- k2: chunk-level scan -> carry-in ----------------
__global__ void k2_carry(float2* __restrict__ ws2) {
    const int idx = blockIdx.x * 256 + threadIdx.x;   // 0..2047
    const int b = idx >> 7;
    const int n = idx & 127;
    const float2 l = ws2[W2_LDP + 127 * 128 + n];
    float cr = 0.f, ci = 0.f;
    for (int c = 0; c < NCH; ++c) {
        const int o = (b * NCH + c) * 128 + n;
        ws2[W2_CIN + o] = make_float2(cr, ci);
        const float2 e = ws2[W2_E + o];
        const float nr = fmaf(l.x, cr, fmaf(-l.y, ci, e.x));
        const float ni = fmaf(l.x, ci, fmaf(l.y, cr, e.y));
        cr = nr; ci = ni;
    }
}

// ================= k3b: bus frags -> tri-cumsum -> x -> GEMM3 -> LDS-transposed y =================
__global__ __launch_bounds__(512, 4) void k3b_out(const float2* __restrict__ ws2,
                                                  const char* __restrict__ busg,
                                                  const unsigned short* __restrict__ ccpack,
                                                  float* __restrict__ y) {
    __shared__ unsigned short lds[32768];     // 64 KB: x tile, then y tile (f32)
    const int tid = threadIdx.x;
    const int lane = tid & 63;
    const int w = tid >> 6;
    const int tl = lane & 15;
    const int gq = (lane >> 4) & 3;
    const int g = blockIdx.x;
    const int b = g >> 6;
    const int c = g & 63;
    const int n = w * 16 + tl;
    const short8v* cc8 = (const short8v*)ccpack;
    const char* busc = busg + (size_t)g * 65536;

    // GEMM2: z = T_lower_ones x Bus (B-fragments direct from global, 16B/lane coalesced)
    short8v ONES, D0, D1;
#pragma unroll
    for (int j = 0; j < 8; ++j) {
        const int sl = gq * 8 + j;
        ONES[j] = (short)0x3F80;
        D0[j] = (sl <= tl) ? (short)0x3F80 : (short)0;
        D1[j] = (sl <= tl + 16) ? (short)0x3F80 : (short)0;
    }
    f32x4 z[8][2];
#pragma unroll
    for (int i = 0; i < 8; ++i) { z[i][0] = (f32x4)0.f; z[i][1] = (f32x4)0.f; }
#pragma unroll
    for (int ks = 0; ks < 4; ++ks) {
        const int sb = ks * 32 + gq * 8;                 // (sb&7)==0
        const int rowr = w * 16 + tl;
        const int rowi = 128 + rowr;
        const short8v b0 = *(const short8v*)(busc + BUS_BYTE(sb, rowr));
        const short8v b1 = *(const short8v*)(busc + BUS_BYTE(sb, rowi));
#pragma unroll
        for (int tt = 0; tt < 8; ++tt) {
            if (tt < 2 * ks) continue;                   // zero block
            const short8v a = (tt == 2 * ks) ? D0 : ((tt == 2 * ks + 1) ? D1 : ONES);
            z[tt][0] = __builtin_amdgcn_mfma_f32_16x16x32_bf16(a, b0, z[tt][0], 0, 0, 0);
            z[tt][1] = __builtin_amdgcn_mfma_f32_16x16x32_bf16(a, b1, z[tt][1], 0, 0, 0);
        }
    }

    // x[t][k''] = Ldp[t] (.) (z + carry), re/im interleaved along k''=2n+parity
    const float2 cin = ws2[W2_CIN + g * 128 + n];
#pragma unroll
    for (int tt = 0; tt < 8; ++tt) {
#pragma unroll
        for (int reg = 0; reg < 4; ++reg) {
            const int r = tt * 16 + gq * 4 + reg;
            const float2 ld = ws2[W2_LDP + r * 128 + n];
            const float zr = z[tt][0][reg] + cin.x;
            const float zi = z[tt][1][reg] + cin.y;
            const float xr = ld.x * zr - ld.y * zi;
            const float xi = ld.x * zi + ld.y * zr;
            union { __hip_bfloat162 h2; unsigned uu; } pk;
            pk.h2 = __float22bfloat162_rn(make_float2(xr, xi));
            const int byte = (r * 512 + n * 4) ^ ((r & 7) << 4);
            *(unsigned*)((char*)lds + byte) = pk.uu;
        }
    }
    __syncthreads();

    // GEMM3: y[t][p]; wave w owns p-tile w, all t
    f32x4 yac[8];
#pragma unroll
    for (int i = 0; i < 8; ++i) yac[i] = (f32x4)0.f;
    __builtin_amdgcn_s_setprio(1);
#pragma unroll
    for (int ks = 0; ks < 8; ++ks) {
        const short8v bfrg = cc8[(w * 8 + ks) * 64 + lane];
#pragma unroll
        for (int tt = 0; tt < 8; ++tt) {
            const int t = tt * 16 + tl;
            const int byte = (t * 512 + (ks * 32 + gq * 8) * 2) ^ ((t & 7) << 4);
            const short8v a = *(const short8v*)((const char*)lds + byte);
            yac[tt] = __builtin_amdgcn_mfma_f32_16x16x32_bf16(a, bfrg, yac[tt], 0, 0, 0);
        }
    }
    __builtin_amdgcn_s_setprio(0);

    // transpose y through LDS (x dead) -> fully coalesced float4 stores
    __syncthreads();    // all waves done reading x
    const int p = w * 16 + tl;
#pragma unroll
    for (int tt = 0; tt < 8; ++tt) {
#pragma unroll
        for (int reg = 0; reg < 4; ++reg) {
            const int t = tt * 16 + gq * 4 + reg;
            const int byte = (t * 512 + p * 4) ^ ((t & 7) << 4);
            *(float*)((char*)lds + byte) = yac[tt][reg];
        }
    }
    __syncthreads();
    float4* yf = (float4*)(y + (size_t)(b * 8192 + c * 128) * 128);
#pragma unroll
    for (int it = 0; it < 8; ++it) {
        const int f4 = it * 512 + tid;
        const int row = f4 >> 5;
        const int col = (f4 & 31) * 4;
        const int byte = (row * 512 + col * 4) ^ ((row & 7) << 4);
        yf[f4] = *(float4*)((char*)lds + byte);
    }
}

// ================= fallback path: R4-proven k1 + k3 (used if ws too small) =================
__global__ __launch_bounds__(512, 4) void k1_end(const float* __restrict__ u,
                                                 float2* __restrict__ ws2,
                                                 const unsigned short* __restrict__ wpack) {
    __shared__ unsigned short lds_u[16384];   // 32 KB
    const int tid = threadIdx.x;
    const int lane = tid & 63;
    const int w = tid >> 6;
    const int tl = lane & 15;
    const int gq = (lane >> 4) & 3;
    const int g = blockIdx.x;
    const int b = g >> 6;
    const int c = g & 63;
    const int n = w * 16 + tl;
    stage_u(u + (size_t)(b * 8192 + c * 128) * 128, lds_u);
    __syncthreads();
    const short8v* wp = (const short8v*)wpack;
    float er = 0.f, ei = 0.f;
#pragma unroll
    for (int h = 0; h < 2; ++h) {
        f32x4 acc[4][2];
#pragma unroll
        for (int i = 0; i < 4; ++i) { acc[i][0] = (f32x4)0.f; acc[i][1] = (f32x4)0.f; }
        __builtin_amdgcn_s_setprio(1);
#pragma unroll
        for (int ks = 0; ks < 4; ++ks) {
            const short8v b0 = wp[(w * 4 + ks) * 64 + lane];
            const short8v b1 = wp[((8 + w) * 4 + ks) * 64 + lane];
#pragma unroll
            for (int tt2 = 0; tt2 < 4; ++tt2) {
                const int t = (h * 4 + tt2) * 16 + tl;
                const int byte = (t * 256 + (ks * 32 + gq * 8) * 2) ^ ((t & 7) << 4);
                const short8v a = *(const short8v*)((const char*)lds_u + byte);
                acc[tt2][0] = __builtin_amdgcn_mfma_f32_16x16x32_bf16(a, b0, acc[tt2][0], 0, 0, 0);
                acc[tt2][1] = __builtin_amdgcn_mfma_f32_16x16x32_bf16(a, b1, acc[tt2][1], 0, 0, 0);
            }
        }
        __builtin_amdgcn_s_setprio(0);
        __builtin_amdgcn_sched_barrier(0);
#pragma unroll
        for (int tt2 = 0; tt2 < 4; ++tt2) {
#pragma unroll
            for (int reg = 0; reg < 4; ++reg) {
                const int r = (h * 4 + tt2) * 16 + gq * 4 + reg;
                const float2 li = ws2[W2_LDINV + r * 128 + n];
                const float br = acc[tt2][0][reg], bi = acc[tt2][1][reg];
                er += li.x * br - li.y * bi;
                ei += li.x * bi + li.y * br;
            }
        }
        __builtin_amdgcn_sched_barrier(0);
    }
    er += __shfl_xor(er, 16); ei += __shfl_xor(ei, 16);
    er += __shfl_xor(er, 32); ei += __shfl_xor(ei, 32);
    const float2 ld = ws2[W2_LDP + 127 * 128 + n];
    if (lane < 16) {
        ws2[W2_E + g * 128 + n] = make_float2(ld.x * er - ld.y * ei,
                                              ld.x * ei + ld.y * er);
    }
}

__global__ __launch_bounds__(512, 4) void k3_main(const float* __restrict__ u,
                                                  const float2* __restrict__ ws2,
                                                  const unsigned short* __restrict__ wpack,
                                                  const unsigned short* __restrict__ ccpack,
                                                  float* __restrict__ y) {
    __shared__ unsigned short lds[32768];     // 64 KB
    const int tid = threadIdx.x;
    const int lane = tid & 63;
    const int w = tid >> 6;
    const int tl = lane & 15;
    const int gq = (lane >> 4) & 3;
    const int g = blockIdx.x;
    const int b = g >> 6;
    const int c = g & 63;
    const int n = w * 16 + tl;
    const short8v* wp = (const short8v*)wpack;
    const short8v* cc8 = (const short8v*)ccpack;

    stage_u(u + (size_t)(b * 8192 + c * 128) * 128, lds);
    __syncthreads();
#pragma unroll
    for (int hh = 0; hh < 2; ++hh) {
        const int h = 1 - hh;
        f32x4 acc[4][2];
#pragma unroll
        for (int i = 0; i < 4; ++i) { acc[i][0] = (f32x4)0.f; acc[i][1] = (f32x4)0.f; }
        __builtin_amdgcn_s_setprio(1);
#pragma unroll
        for (int ks = 0; ks < 4; ++ks) {
            const short8v b0 = wp[(w * 4 + ks) * 64 + lane];
            const short8v b1 = wp[((8 + w) * 4 + ks) * 64 + lane];
#pragma unroll
            for (int tt2 = 0; tt2 < 4; ++tt2) {
                const int t = (h * 4 + tt2) * 16 + tl;
                const int byte = (t * 256 + (ks * 32 + gq * 8) * 2) ^ ((t & 7) << 4);
                const short8v a = *(const short8v*)((const char*)lds + byte);
                acc[tt2][0] = __builtin_amdgcn_mfma_f32_16x16x32_bf16(a, b0, acc[tt2][0], 0, 0, 0);
                acc[tt2][1] = __builtin_amdgcn_mfma_f32_16x16x32_bf16(a, b1, acc[tt2][1], 0, 0, 0);
            }
        }
        __builtin_amdgcn_s_setprio(0);
        __builtin_amdgcn_sched_barrier(0);
        if (h == 0) __syncthreads();
#pragma unroll
        for (int tt2 = 0; tt2 < 4; ++tt2) {
            float vr[4], vi[4];
#pragma unroll
            for (int reg = 0; reg < 4; ++reg) {
                const int r = (h * 4 + tt2) * 16 + gq * 4 + reg;
                const float2 li = ws2[W2_LDINV + r * 128 + n];
                const float br = acc[tt2][0][reg], bi = acc[tt2][1][reg];
                vr[reg] = li.x * br - li.y * bi;
                vi[reg] = li.x * bi + li.y * br;
            }
            const int s0 = (h * 4 + tt2) * 16 + gq * 4;
            const int rowr = w * 16 + tl;
            const int rowi = 128 + rowr;
            *(short4v*)((char*)lds + BUS_BYTE(s0, rowr)) = pack4(vr[0], vr[1], vr[2], vr[3]);
            *(short4v*)((char*)lds + BUS_BYTE(s0, rowi)) = pack4(vi[0], vi[1], vi[2], vi[3]);
        }
        __builtin_amdgcn_sched_barrier(0);
    }
    short8v ONES, D0, D1;
#pragma unroll
    for (int j = 0; j < 8; ++j) {
        const int sl = gq * 8 + j;
        ONES[j] = (short)0x3F80;
        D0[j] = (sl <= tl) ? (short)0x3F80 : (short)0;
        D1[j] = (sl <= tl + 16) ? (short)0x3F80 : (short)0;
    }
    f32x4 z[8][2];
#pragma unroll
    for (int i = 0; i < 8; ++i) { z[i][0] = (f32x4)0.f; z[i][1] = (f32x4)0.f; }
#pragma unroll
    for (int ks = 0; ks < 4; ++ks) {
        const int sb = ks * 32 + gq * 8;
        const int rowr = w * 16 + tl;
        const int rowi = 128 + rowr;
        const short8v b0 = *(const short8v*)((const char*)lds + BUS_BYTE(sb, rowr));
        const short8v b1 = *(const short8v*)((const char*)lds + BUS_BYTE(sb, rowi));
#pragma unroll
        for (int tt = 0; tt < 8; ++tt) {
            if (tt < 2 * ks) continue;
            const short8v a = (tt == 2 * ks) ? D0 : ((tt == 2 * ks + 1) ? D1 : ONES);
            z[tt][0] = __builtin_amdgcn_mfma_f32_16x16x32_bf16(a, b0, z[tt][0], 0, 0, 0);
            z[tt][1] = __builtin_amdgcn_mfma_f32_16x16x32_bf16(a, b1, z[tt][1], 0, 0, 0);
        }
    }
    __syncthreads();
    const float2 cin = ws2[W2_CIN + g * 128 + n];
#pragma unroll
    for (int tt = 0; tt < 8; ++tt) {
#pragma unroll
        for (int reg = 0; reg < 4; ++reg) {
            const int r = tt * 16 + gq * 4 + reg;
            const float2 ld = ws2[W2_LDP + r * 128 + n];
            const float zr = z[tt][0][reg] + cin.x;
            const float zi = z[tt][1][reg] + cin.y;
            const float xr = ld.x * zr - ld.y * zi;
            const float xi = ld.x * zi + ld.y * zr;
            union { __hip_bfloat162 h2; unsigned uu; } pk;
            pk.h2 = __float22bfloat162_rn(make_float2(xr, xi));
            const int byte = (r * 512 + n * 4) ^ ((r & 7) << 4);
            *(unsigned*)((char*)lds + byte) = pk.uu;
        }
    }
    __syncthreads();
    f32x4 yac[8];
#pragma unroll
    for (int i = 0; i < 8; ++i) yac[i] = (f32x4)0.f;
    __builtin_amdgcn_s_setprio(1);
#pragma unroll
    for (int ks = 0; ks < 8; ++ks) {
        const short8v bfrg = cc8[(w * 8 + ks) * 64 + lane];
#pragma unroll
        for (int tt = 0; tt < 8; ++tt) {
            const int t = tt * 16 + tl;
            const int byte = (t * 512 + (ks * 32 + gq * 8) * 2) ^ ((t & 7) << 4);
            const short8v a = *(const short8v*)((const char*)lds + byte);
            yac[tt] = __builtin_amdgcn_mfma_f32_16x16x32_bf16(a, bfrg, yac[tt], 0, 0, 0);
        }
    }
    __builtin_amdgcn_s_setprio(0);
    const int p = w * 16 + tl;
    float* yrow = y + (size_t)(b * 8192 + c * 128) * 128;
#pragma unroll
    for (int tt = 0; tt < 8; ++tt) {
#pragma unroll
        for (int reg = 0; reg < 4; ++reg) {
            const int t = tt * 16 + gq * 4 + reg;
            yrow[t * 128 + p] = yac[tt][reg];
        }
    }
}

extern "C" void kernel_launch(void* const* d_in, const int* in_sizes, int n_in,
                              void* d_out, int out_size, void* d_ws, size_t ws_size,
                              hipStream_t stream) {
    const float* u     = (const float*)d_in[0];
    const float* lp    = (const float*)d_in[1];
    const float* bp    = (const float*)d_in[2];
    const float* cp    = (const float*)d_in[3];
    const float* delta = (const float*)d_in[4];
    float* y  = (float*)d_out;
    float2* ws2 = (float2*)d_ws;
    unsigned short* wpack  = (unsigned short*)((char*)d_ws + WS_WPACK_BYTE);
    unsigned short* ccpack = (unsigned short*)((char*)d_ws + WS_CCPACK_BYTE);
    char* busg = (char*)d_ws + WS_BUS_BYTE;

    k0_all<<<256, 512, 0, stream>>>(lp, bp, cp, delta, ws2, wpack, ccpack);

    if (ws_size >= WS_NEED) {
        // single-u-pass split path
        k3a_bus <<<NCHUNKS, 512, 0, stream>>>(u, ws2, wpack, busg);
        k2_carry<<<8, 256, 0, stream>>>(ws2);
        k3b_out <<<NCHUNKS, 512, 0, stream>>>(ws2, busg, ccpack, y);
    } else {
        // R4-proven fallback (u read twice)
        k1_end  <<<NCHUNKS, 512, 0, stream>>>(u, ws2, wpack);
        k2_carry<<<8, 256, 0, stream>>>(ws2);
        k3_main <<<NCHUNKS, 512, 0, stream>>>(u, ws2, wpack, ccpack, y);
    }
}

// Round 14
// 84.488 us; speedup vs baseline: 1.0312x; 1.0312x over previous
//
#include <hip/hip_runtime.h>
#include <hip/hip_bf16.h>

// Problem: B=16, T=8192, M=P=128, N2=128. Chunks: L=128, 64/batch, 1024 total.
// R14: split path; k3a = half-pipelined stage -> GEMM1 -> scale -> global bus + E
// (no laundering, (512,4) for exact 2-round dispatch); k3b = bus -> tri-cumsum ->
// x -> GEMM3 -> LDS-transposed y. Merged k0. Fallback to R4 pair if ws too small.
#define LCH 128
#define NCH 64
#define NCHUNKS 1024

typedef __attribute__((ext_vector_type(8))) short short8v;
typedef __attribute__((ext_vector_type(4))) short short4v;
typedef __attribute__((ext_vector_type(4))) float f32x4;

// ws layout: float2 region, packs, then bus.
#define W2_LDINV 0          // [128 r][128 n]  Ld^{-(r+1)}   (float2 idx)
#define W2_LDP   16384      // [128 r][128 n]  Ld^{r+1}
#define W2_E     32768      // [1024 g][128 n]
#define W2_CIN   163840     // [1024 g][128 n]
#define WS_WPACK_BYTE  2359296              // 32768 bf16: [ntile16][ks4][lane64][j8]
#define WS_CCPACK_BYTE (2359296 + 65536)    // 32768 bf16: [ptile8][ks8][lane64][j8]
#define WS_BUS_BYTE    (2359296 + 131072)   // 1024 chunks x 64 KB bf16 bus
#define WS_NEED ((size_t)WS_BUS_BYTE + (size_t)NCHUNKS * 65536)

// bus layout (LDS and global, byte-identical): byte(s,n') = (s>>3)*4096 + n'*16 + (s&7)*2
#define BUS_BYTE(s, np) ((((s) >> 3) * 4096) + ((np) * 16) + (((s) & 7) * 2))

__device__ inline unsigned short f2bf(float f) {
    union { __hip_bfloat16 h; unsigned short u; } v;
    v.h = __float2bfloat16(f);
    return v.u;
}
__device__ inline short4v pack4(float a, float b, float c, float d) {
    union { __hip_bfloat162 h2[2]; short4v s4; } pk;
    pk.h2[0] = __float22bfloat162_rn(make_float2(a, b));
    pk.h2[1] = __float22bfloat162_rn(make_float2(c, d));
    return pk.s4;
}

// ---------------- k0: all setup in one launch (256 blocks x 512) ----------------
__global__ void k0_all(const float* __restrict__ lp, const float* __restrict__ bp,
                       const float* __restrict__ cp, const float* __restrict__ delta,
                       float2* __restrict__ ws2, unsigned short* __restrict__ wpack,
                       unsigned short* __restrict__ ccpack) {
    const int r = blockIdx.x;
    const int tid = threadIdx.x;
    if (r < 128) {
        if (tid < 256) {
            const int n = tid & 127;
            const double d = (double)delta[0];
            const double lre = -exp((double)lp[n]);
            const double lim = (double)lp[128 + n];
            const double kk = (double)(r + 1) * d;
            if (tid < 128) {
                const double mag = exp(-lre * kk);
                ws2[W2_LDINV + r * 128 + n] = make_float2((float)(mag * cos(lim * kk)),
                                                          (float)(-mag * sin(lim * kk)));
            } else {
                const double mag = exp(lre * kk);
                ws2[W2_LDP + r * 128 + n] = make_float2((float)(mag * cos(lim * kk)),
                                                        (float)(mag * sin(lim * kk)));
            }
        }
    } else if (r < 192) {
        const int gid = (r - 128) * 512 + tid;         // 0..32767
        const int j = gid & 7;
        const int lane = (gid >> 3) & 63;
        const int ks = (gid >> 9) & 3;
        const int ntile = gid >> 11;
        const int np = ntile * 16 + (lane & 15);
        const int m = ks * 32 + ((lane >> 4) & 3) * 8 + j;
        const int n = np & 127;
        const double d = (double)delta[0];
        const double lre = -exp((double)lp[n]);
        const double lim = (double)lp[128 + n];
        const double er = exp(lre * d);
        const double ldr = er * cos(lim * d), ldi = er * sin(lim * d);
        const double nr = ldr - 1.0, ni = ldi;
        const double den = lre * lre + lim * lim;
        const double cr = (nr * lre + ni * lim) / den;
        const double ci = (ni * lre - nr * lim) / den;
        const double br = (double)bp[n * 128 + m];
        const double bi = (double)bp[16384 + n * 128 + m];
        const double v = (np < 128) ? (cr * br - ci * bi) : (cr * bi + ci * br);
        wpack[gid] = f2bf((float)v);
    } else {
        const int gid = (r - 192) * 512 + tid;         // 0..32767
        const int j = gid & 7;
        const int lane = (gid >> 3) & 63;
        const int ks = (gid >> 9) & 7;
        const int ptile = gid >> 12;
        const int p = ptile * 16 + (lane & 15);
        const int k = ks * 32 + ((lane >> 4) & 3) * 8 + j;
        const int n = k >> 1;
        const float v = ((k & 1) == 0) ? 2.0f * cp[p * 128 + n]
                                       : -2.0f * cp[16384 + p * 128 + n];
        ccpack[gid] = f2bf(v);
    }
}

// ---------------- shared helper: stage u chunk -> LDS bf16 [t][m], XOR swizzle ----------------
__device__ inline void stage_u(const float* __restrict__ uchunk, unsigned short* lds_u) {
    const float4* uf = (const float4*)uchunk;
    const int tid = threadIdx.x;
#pragma unroll
    for (int it = 0; it < 8; ++it) {
        const int f4 = it * 512 + tid;
        const float4 v = uf[f4];
        const int t = f4 >> 5;
        const int m = (f4 & 31) * 4;
        const int byte = (t * 256 + m * 2) ^ ((t & 7) << 4);
        *(short4v*)((char*)lds_u + byte) = pack4(v.x, v.y, v.z, v.w);
    }
}

// ================= k3a: half-pipelined stage -> GEMM1 -> scale -> global bus + E =================
// Half h = u rows [64h, 64h+64). Bus is GLOBAL, so LDS halves are independent:
// stage h0; issue h1 loads; barrier; {GEMM1-h0 + scale + store} || stage h1 (disjoint
// LDS rows, no barrier needed between them); barrier; GEMM1-h1 + scale + store + E.
// (512,4): 2 blocks/CU -> 1024 blocks = exactly 2 dispatch rounds; peak ~88 regs, no spill.
__global__ __launch_bounds__(512, 4) void k3a_bus(const float* __restrict__ u,
                                                  float2* __restrict__ ws2,
                                                  const unsigned short* __restrict__ wpack,
                                                  char* __restrict__ busg) {
    __shared__ unsigned short lds_u[16384];   // 32 KB
    const int tid = threadIdx.x;
    const int lane = tid & 63;
    const int w = tid >> 6;
    const int tl = lane & 15;
    const int gq = (lane >> 4) & 3;
    const int g = blockIdx.x;
    const int b = g >> 6;
    const int c = g & 63;
    const int n = w * 16 + tl;
    const short8v* wp = (const short8v*)wpack;
    char* busc = busg + (size_t)g * 65536;
    const float4* uf = (const float4*)(u + (size_t)(b * 8192 + c * 128) * 128);

    // prefetch + stage half 0 (f4 idx 0..2047 -> rows 0..63)
    {
        float4 p0 = uf[tid], p1 = uf[512 + tid], p2 = uf[1024 + tid], p3 = uf[1536 + tid];
#pragma unroll
        for (int it = 0; it < 4; ++it) {
            const float4 v = (it == 0) ? p0 : (it == 1) ? p1 : (it == 2) ? p2 : p3;
            const int f4 = it * 512 + tid;
            const int t = f4 >> 5;
            const int m = (f4 & 31) * 4;
            const int byte = (t * 256 + m * 2) ^ ((t & 7) << 4);
            *(short4v*)((char*)lds_u + byte) = pack4(v.x, v.y, v.z, v.w);
        }
    }
    // issue half-1 loads; latency hides under GEMM1-h0 below
    float4 q0 = uf[2048 + tid], q1 = uf[2560 + tid], q2 = uf[3072 + tid], q3 = uf[3584 + tid];
    __builtin_amdgcn_sched_barrier(0);
    __syncthreads();                          // half 0 staged

    float er = 0.f, ei = 0.f;

    // ---- GEMM1-h0 + scale + bus store ----
    {
        f32x4 acc[4][2];
#pragma unroll
        for (int i = 0; i < 4; ++i) { acc[i][0] = (f32x4)0.f; acc[i][1] = (f32x4)0.f; }
        __builtin_amdgcn_s_setprio(1);
#pragma unroll
        for (int ks = 0; ks < 4; ++ks) {
            const short8v b0 = wp[(w * 4 + ks) * 64 + lane];
            const short8v b1 = wp[((8 + w) * 4 + ks) * 64 + lane];
#pragma unroll
            for (int tt2 = 0; tt2 < 4; ++tt2) {
                const int t = tt2 * 16 + tl;
                const int byte = (t * 256 + (ks * 32 + gq * 8) * 2) ^ ((t & 7) << 4);
                const short8v a = *(const short8v*)((const char*)lds_u + byte);
                acc[tt2][0] = __builtin_amdgcn_mfma_f32_16x16x32_bf16(a, b0, acc[tt2][0], 0, 0, 0);
                acc[tt2][1] = __builtin_amdgcn_mfma_f32_16x16x32_bf16(a, b1, acc[tt2][1], 0, 0, 0);
            }
        }
        __builtin_amdgcn_s_setprio(0);
#pragma unroll
        for (int tt2 = 0; tt2 < 4; ++tt2) {
            float vr[4], vi[4];
#pragma unroll
            for (int reg = 0; reg < 4; ++reg) {
                const int rr = tt2 * 16 + gq * 4 + reg;
                const float2 li = ws2[W2_LDINV + rr * 128 + n];
                const float br = acc[tt2][0][reg], bi = acc[tt2][1][reg];
                vr[reg] = li.x * br - li.y * bi;
                vi[reg] = li.x * bi + li.y * br;
                er += vr[reg];
                ei += vi[reg];
            }
            const int s0 = tt2 * 16 + gq * 4;
            const int rowr = w * 16 + tl;
            const int rowi = 128 + rowr;
            *(short4v*)(busc + BUS_BYTE(s0, rowr)) = pack4(vr[0], vr[1], vr[2], vr[3]);
            *(short4v*)(busc + BUS_BYTE(s0, rowi)) = pack4(vi[0], vi[1], vi[2], vi[3]);
        }
    }

    // stage half 1 (rows 64..127 — disjoint from h0 reads above; compiler interleaves)
    {
#pragma unroll
        for (int it = 0; it < 4; ++it) {
            const float4 v = (it == 0) ? q0 : (it == 1) ? q1 : (it == 2) ? q2 : q3;
            const int f4 = 2048 + it * 512 + tid;
            const int t = f4 >> 5;
            const int m = (f4 & 31) * 4;
            const int byte = (t * 256 + m * 2) ^ ((t & 7) << 4);
            *(short4v*)((char*)lds_u + byte) = pack4(v.x, v.y, v.z, v.w);
        }
    }
    __syncthreads();                          // half 1 staged

    // ---- GEMM1-h1 + scale + bus store + E ----
    {
        f32x4 acc[4][2];
#pragma unroll
        for (int i = 0; i < 4; ++i) { acc[i][0] = (f32x4)0.f; acc[i][1] = (f32x4)0.f; }
        __builtin_amdgcn_s_setprio(1);
#pragma unroll
        for (int ks = 0; ks < 4; ++ks) {
            const short8v b0 = wp[(w * 4 + ks) * 64 + lane];
            const short8v b1 = wp[((8 + w) * 4 + ks) * 64 + lane];
#pragma unroll
            for (int tt2 = 0; tt2 < 4; ++tt2) {
                const int t = (4 + tt2) * 16 + tl;
                const int byte = (t * 256 + (ks * 32 + gq * 8) * 2) ^ ((t & 7) << 4);
                const short8v a = *(const short8v*)((const char*)lds_u + byte);
                acc[tt2][0] = __builtin_amdgcn_mfma_f32_16x16x32_bf16(a, b0, acc[tt2][0], 0, 0, 0);
                acc[tt2][1] = __builtin_amdgcn_mfma_f32_16x16x32_bf16(a, b1, acc[tt2][1], 0, 0, 0);
            }
        }
        __builtin_amdgcn_s_setprio(0);
#pragma unroll
        for (int tt2 = 0; tt2 < 4; ++tt2) {
            float vr[4], vi[4];
#pragma unroll
            for (int reg = 0; reg < 4; ++reg) {
                const int rr = (4 + tt2) * 16 + gq * 4 + reg;
                const float2 li = ws2[W2_LDINV + rr * 128 + n];
                const float br = acc[tt2][0][reg], bi = acc[tt2][1][reg];
                vr[reg] = li.x * br - li.y * bi;
                vi[reg] = li.x * bi + li.y * br;
                er += vr[reg];
                ei += vi[reg];
            }
            const int s0 = (4 + tt2) * 16 + gq * 4;
            const int rowr = w * 16 + tl;
            const int rowi = 128 + rowr;
            *(short4v*)(busc + BUS_BYTE(s0, rowr)) = pack4(vr[0], vr[1], vr[2], vr[3]);
            *(short4v*)(busc + BUS_BYTE(s0, rowi)) = pack4(vi[0], vi[1], vi[2], vi[3]);
        }
    }

    // E[g][n] = Ld^128 * sum_s (Ldinv[s] (.) Bu[s,n])
    er += __shfl_xor(er, 16); ei += __shfl_xor(ei, 16);
    er += __shfl_xor(er, 32); ei += __shfl_xor(ei, 32);
    const float2 ld = ws2[W2_LDP + 127 * 128 + n];
    if (lane < 16) {
        ws2[W2_E + g * 128 + n] = make_float2(ld.x * er - ld.y * ei,
                                              ld.x * ei + ld.y * er);
    }
}

// ---------------- k2: chunk-level scan -> carry-in ----------------
__global__ void k2_carry(float2* __restrict__ ws2) {
    const int idx = blockIdx.x * 256 + threadIdx.x;   // 0..2047
    const int b = idx >> 7;
    const int n = idx & 127;
    const float2 l = ws2[W2_LDP + 127 * 128 + n];
    float cr = 0.f, ci = 0.f;
    for (int c = 0; c < NCH; ++c) {
        const int o = (b * NCH + c) * 128 + n;
        ws2[W2_CIN + o] = make_float2(cr, ci);
        const float2 e = ws2[W2_E + o];
        const float nr = fmaf(l.x, cr, fmaf(-l.y, ci, e.x));
        const float ni = fmaf(l.x, ci, fmaf(l.y, cr, e.y));
        cr = nr; ci = ni;
    }
}

// ================= k3b: bus frags -> tri-cumsum -> x -> GEMM3 -> LDS-transposed y =================
__global__ __launch_bounds__(512, 4) void k3b_out(const float2* __restrict__ ws2,
                                                  const char* __restrict__ busg,
                                                  const unsigned short* __restrict__ ccpack,
                                                  float* __restrict__ y) {
    __shared__ unsigned short lds[32768];     // 64 KB: x tile, then y tile (f32)
    const int tid = threadIdx.x;
    const int lane = tid & 63;
    const int w = tid >> 6;
    const int tl = lane & 15;
    const int gq = (lane >> 4) & 3;
    const int g = blockIdx.x;
    const int b = g >> 6;
    const int c = g & 63;
    const int n = w * 16 + tl;
    const short8v* cc8 = (const short8v*)ccpack;
    const char* busc = busg + (size_t)g * 65536;

    // GEMM2: z = T_lower_ones x Bus (B-fragments direct from global, 16B/lane coalesced)
    short8v ONES, D0, D1;
#pragma unroll
    for (int j = 0; j < 8; ++j) {
        const int sl = gq * 8 + j;
        ONES[j] = (short)0x3F80;
        D0[j] = (sl <= tl) ? (short)0x3F80 : (short)0;
        D1[j] = (sl <= tl + 16) ? (short)0x3F80 : (short)0;
    }
    f32x4 z[8][2];
#pragma unroll
    for (int i = 0; i < 8; ++i) { z[i][0] = (f32x4)0.f; z[i][1] = (f32x4)0.f; }
    __builtin_amdgcn_s_setprio(1);
#pragma unroll
    for (int ks = 0; ks < 4; ++ks) {
        const int sb = ks * 32 + gq * 8;                 // (sb&7)==0
        const int rowr = w * 16 + tl;
        const int rowi = 128 + rowr;
        const short8v b0 = *(const short8v*)(busc + BUS_BYTE(sb, rowr));
        const short8v b1 = *(const short8v*)(busc + BUS_BYTE(sb, rowi));
#pragma unroll
        for (int tt = 0; tt < 8; ++tt) {
            if (tt < 2 * ks) continue;                   // zero block
            const short8v a = (tt == 2 * ks) ? D0 : ((tt == 2 * ks + 1) ? D1 : ONES);
            z[tt][0] = __builtin_amdgcn_mfma_f32_16x16x32_bf16(a, b0, z[tt][0], 0, 0, 0);
            z[tt][1] = __builtin_amdgcn_mfma_f32_16x16x32_bf16(a, b1, z[tt][1], 0, 0, 0);
        }
    }
    __builtin_amdgcn_s_setprio(0);

    // x[t][k''] = Ldp[t] (.) (z + carry), re/im interleaved along k''=2n+parity
    const float2 cin = ws2[W2_CIN + g * 128 + n];
#pragma unroll
    for (int tt = 0; tt < 8; ++tt) {
#pragma unroll
        for (int reg = 0; reg < 4; ++reg) {
            const int r = tt * 16 + gq * 4 + reg;
            const float2 ld = ws2[W2_LDP + r * 128 + n];
            const float zr = z[tt][0][reg] + cin.x;
            const float zi = z[tt][1][reg] + cin.y;
            const float xr = ld.x * zr - ld.y * zi;
            const float xi = ld.x * zi + ld.y * zr;
            union { __hip_bfloat162 h2; unsigned uu; } pk;
            pk.h2 = __float22bfloat162_rn(make_float2(xr, xi));
            const int byte = (r * 512 + n * 4) ^ ((r & 7) << 4);
            *(unsigned*)((char*)lds + byte) = pk.uu;
        }
    }
    __syncthreads();

    // GEMM3: y[t][p]; wave w owns p-tile w, all t
    f32x4 yac[8];
#pragma unroll
    for (int i = 0; i < 8; ++i) yac[i] = (f32x4)0.f;
    __builtin_amdgcn_s_setprio(1);
#pragma unroll
    for (int ks = 0; ks < 8; ++ks) {
        const short8v bfrg = cc8[(w * 8 + ks) * 64 + lane];
#pragma unroll
        for (int tt = 0; tt < 8; ++tt) {
            const int t = tt * 16 + tl;
            const int byte = (t * 512 + (ks * 32 + gq * 8) * 2) ^ ((t & 7) << 4);
            const short8v a = *(const short8v*)((const char*)lds + byte);
            yac[tt] = __builtin_amdgcn_mfma_f32_16x16x32_bf16(a, bfrg, yac[tt], 0, 0, 0);
        }
    }
    __builtin_amdgcn_s_setprio(0);

    // transpose y through LDS (x dead) -> fully coalesced float4 stores
    __syncthreads();    // all waves done reading x
    const int p = w * 16 + tl;
#pragma unroll
    for (int tt = 0; tt < 8; ++tt) {
#pragma unroll
        for (int reg = 0; reg < 4; ++reg) {
            const int t = tt * 16 + gq * 4 + reg;
            const int byte = (t * 512 + p * 4) ^ ((t & 7) << 4);
            *(float*)((char*)lds + byte) = yac[tt][reg];
        }
    }
    __syncthreads();
    float4* yf = (float4*)(y + (size_t)(b * 8192 + c * 128) * 128);
#pragma unroll
    for (int it = 0; it < 8; ++it) {
        const int f4 = it * 512 + tid;
        const int row = f4 >> 5;
        const int col = (f4 & 31) * 4;
        const int byte = (row * 512 + col * 4) ^ ((row & 7) << 4);
        yf[f4] = *(float4*)((char*)lds + byte);
    }
}

// ================= fallback path: R4-proven k1 + k3 (used if ws too small) =================
__global__ __launch_bounds__(512, 4) void k1_end(const float* __restrict__ u,
                                                 float2* __restrict__ ws2,
                                                 const unsigned short* __restrict__ wpack) {
    __shared__ unsigned short lds_u[16384];   // 32 KB
    const int tid = threadIdx.x;
    const int lane = tid & 63;
    const int w = tid >> 6;
    const int tl = lane & 15;
    const int gq = (lane >> 4) & 3;
    const int g = blockIdx.x;
    const int b = g >> 6;
    const int c = g & 63;
    const int n = w * 16 + tl;
    stage_u(u + (size_t)(b * 8192 + c * 128) * 128, lds_u);
    __syncthreads();
    const short8v* wp = (const short8v*)wpack;
    float er = 0.f, ei = 0.f;
#pragma unroll
    for (int h = 0; h < 2; ++h) {
        f32x4 acc[4][2];
#pragma unroll
        for (int i = 0; i < 4; ++i) { acc[i][0] = (f32x4)0.f; acc[i][1] = (f32x4)0.f; }
        __builtin_amdgcn_s_setprio(1);
#pragma unroll
        for (int ks = 0; ks < 4; ++ks) {
            const short8v b0 = wp[(w * 4 + ks) * 64 + lane];
            const short8v b1 = wp[((8 + w) * 4 + ks) * 64 + lane];
#pragma unroll
            for (int tt2 = 0; tt2 < 4; ++tt2) {
                const int t = (h * 4 + tt2) * 16 + tl;
                const int byte = (t * 256 + (ks * 32 + gq * 8) * 2) ^ ((t & 7) << 4);
                const short8v a = *(const short8v*)((const char*)lds_u + byte);
                acc[tt2][0] = __builtin_amdgcn_mfma_f32_16x16x32_bf16(a, b0, acc[tt2][0], 0, 0, 0);
                acc[tt2][1] = __builtin_amdgcn_mfma_f32_16x16x32_bf16(a, b1, acc[tt2][1], 0, 0, 0);
            }
        }
        __builtin_amdgcn_s_setprio(0);
        __builtin_amdgcn_sched_barrier(0);
#pragma unroll
        for (int tt2 = 0; tt2 < 4; ++tt2) {
#pragma unroll
            for (int reg = 0; reg < 4; ++reg) {
                const int r = (h * 4 + tt2) * 16 + gq * 4 + reg;
                const float2 li = ws2[W2_LDINV + r * 128 + n];
                const float br = acc[tt2][0][reg], bi = acc[tt2][1][reg];
                er += li.x * br - li.y * bi;
                ei += li.x * bi + li.y * br;
            }
        }
        __builtin_amdgcn_sched_barrier(0);
    }
    er += __shfl_xor(er, 16); ei += __shfl_xor(ei, 16);
    er += __shfl_xor(er, 32); ei += __shfl_xor(ei, 32);
    const float2 ld = ws2[W2_LDP + 127 * 128 + n];
    if (lane < 16) {
        ws2[W2_E + g * 128 + n] = make_float2(ld.x * er - ld.y * ei,
                                              ld.x * ei + ld.y * er);
    }
}

__global__ __launch_bounds__(512, 4) void k3_main(const float* __restrict__ u,
                                                  const float2* __restrict__ ws2,
                                                  const unsigned short* __restrict__ wpack,
                                                  const unsigned short* __restrict__ ccpack,
                                                  float* __restrict__ y) {
    __shared__ unsigned short lds[32768];     // 64 KB
    const int tid = threadIdx.x;
    const int lane = tid & 63;
    const int w = tid >> 6;
    const int tl = lane & 15;
    const int gq = (lane >> 4) & 3;
    const int g = blockIdx.x;
    const int b = g >> 6;
    const int c = g & 63;
    const int n = w * 16 + tl;
    const short8v* wp = (const short8v*)wpack;
    const short8v* cc8 = (const short8v*)ccpack;

    stage_u(u + (size_t)(b * 8192 + c * 128) * 128, lds);
    __syncthreads();
#pragma unroll
    for (int hh = 0; hh < 2; ++hh) {
        const int h = 1 - hh;
        f32x4 acc[4][2];
#pragma unroll
        for (int i = 0; i < 4; ++i) { acc[i][0] = (f32x4)0.f; acc[i][1] = (f32x4)0.f; }
        __builtin_amdgcn_s_setprio(1);
#pragma unroll
        for (int ks = 0; ks < 4; ++ks) {
            const short8v b0 = wp[(w * 4 + ks) * 64 + lane];
            const short8v b1 = wp[((8 + w) * 4 + ks) * 64 + lane];
#pragma unroll
            for (int tt2 = 0; tt2 < 4; ++tt2) {
                const int t = (h * 4 + tt2) * 16 + tl;
                const int byte = (t * 256 + (ks * 32 + gq * 8) * 2) ^ ((t & 7) << 4);
                const short8v a = *(const short8v*)((const char*)lds + byte);
                acc[tt2][0] = __builtin_amdgcn_mfma_f32_16x16x32_bf16(a, b0, acc[tt2][0], 0, 0, 0);
                acc[tt2][1] = __builtin_amdgcn_mfma_f32_16x16x32_bf16(a, b1, acc[tt2][1], 0, 0, 0);
            }
        }
        __builtin_amdgcn_s_setprio(0);
        __builtin_amdgcn_sched_barrier(0);
        if (h == 0) __syncthreads();
#pragma unroll
        for (int tt2 = 0; tt2 < 4; ++tt2) {
            float vr[4], vi[4];
#pragma unroll
            for (int reg = 0; reg < 4; ++reg) {
                const int r = (h * 4 + tt2) * 16 + gq * 4 + reg;
                const float2 li = ws2[W2_LDINV + r * 128 + n];
                const float br = acc[tt2][0][reg], bi = acc[tt2][1][reg];
                vr[reg] = li.x * br - li.y * bi;
                vi[reg] = li.x * bi + li.y * br;
            }
            const int s0 = (h * 4 + tt2) * 16 + gq * 4;
            const int rowr = w * 16 + tl;
            const int rowi = 128 + rowr;
            *(short4v*)((char*)lds + BUS_BYTE(s0, rowr)) = pack4(vr[0], vr[1], vr[2], vr[3]);
            *(short4v*)((char*)lds + BUS_BYTE(s0, rowi)) = pack4(vi[0], vi[1], vi[2], vi[3]);
        }
        __builtin_amdgcn_sched_barrier(0);
    }
    short8v ONES, D0, D1;
#pragma unroll
    for (int j = 0; j < 8; ++j) {
        const int sl = gq * 8 + j;
        ONES[j] = (short)0x3F80;
        D0[j] = (sl <= tl) ? (short)0x3F80 : (short)0;
        D1[j] = (sl <= tl + 16) ? (short)0x3F80 : (short)0;
    }
    f32x4 z[8][2];
#pragma unroll
    for (int i = 0; i < 8; ++i) { z[i][0] = (f32x4)0.f; z[i][1] = (f32x4)0.f; }
#pragma unroll
    for (int ks = 0; ks < 4; ++ks) {
        const int sb = ks * 32 + gq * 8;
        const int rowr = w * 16 + tl;
        const int rowi = 128 + rowr;
        const short8v b0 = *(const short8v*)((const char*)lds + BUS_BYTE(sb, rowr));
        const short8v b1 = *(const short8v*)((const char*)lds + BUS_BYTE(sb, rowi));
#pragma unroll
        for (int tt = 0; tt < 8; ++tt) {
            if (tt < 2 * ks) continue;
            const short8v a = (tt == 2 * ks) ? D0 : ((tt == 2 * ks + 1) ? D1 : ONES);
            z[tt][0] = __builtin_amdgcn_mfma_f32_16x16x32_bf16(a, b0, z[tt][0], 0, 0, 0);
            z[tt][1] = __builtin_amdgcn_mfma_f32_16x16x32_bf16(a, b1, z[tt][1], 0, 0, 0);
        }
    }
    __syncthreads();
    const float2 cin = ws2[W2_CIN + g * 128 + n];
#pragma unroll
    for (int tt = 0; tt < 8; ++tt) {
#pragma unroll
        for (int reg = 0; reg < 4; ++reg) {
            const int r = tt * 16 + gq * 4 + reg;
            const float2 ld = ws2[W2_LDP + r * 128 + n];
            const float zr = z[tt][0][reg] + cin.x;
            const float zi = z[tt][1][reg] + cin.y;
            const float xr = ld.x * zr - ld.y * zi;
            const float xi = ld.x * zi + ld.y * zr;
            union { __hip_bfloat162 h2; unsigned uu; } pk;
            pk.h2 = __float22bfloat162_rn(make_float2(xr, xi));
            const int byte = (r * 512 + n * 4) ^ ((r & 7) << 4);
            *(unsigned*)((char*)lds + byte) = pk.uu;
        }
    }
    __syncthreads();
    f32x4 yac[8];
#pragma unroll
    for (int i = 0; i < 8; ++i) yac[i] = (f32x4)0.f;
    __builtin_amdgcn_s_setprio(1);
#pragma unroll
    for (int ks = 0; ks < 8; ++ks) {
        const short8v bfrg = cc8[(w * 8 + ks) * 64 + lane];
#pragma unroll
        for (int tt = 0; tt < 8; ++tt) {
            const int t = tt * 16 + tl;
            const int byte = (t * 512 + (ks * 32 + gq * 8) * 2) ^ ((t & 7) << 4);
            const short8v a = *(const short8v*)((const char*)lds + byte);
            yac[tt] = __builtin_amdgcn_mfma_f32_16x16x32_bf16(a, bfrg, yac[tt], 0, 0, 0);
        }
    }
    __builtin_amdgcn_s_setprio(0);
    const int p = w * 16 + tl;
    float* yrow = y + (size_t)(b * 8192 + c * 128) * 128;
#pragma unroll
    for (int tt = 0; tt < 8; ++tt) {
#pragma unroll
        for (int reg = 0; reg < 4; ++reg) {
            const int t = tt * 16 + gq * 4 + reg;
            yrow[t * 128 + p] = yac[tt][reg];
        }
    }
}

extern "C" void kernel_launch(void* const* d_in, const int* in_sizes, int n_in,
                              void* d_out, int out_size, void* d_ws, size_t ws_size,
                              hipStream_t stream) {
    const float* u     = (const float*)d_in[0];
    const float* lp    = (const float*)d_in[1];
    const float* bp    = (const float*)d_in[2];
    const float* cp    = (const float*)d_in[3];
    const float* delta = (const float*)d_in[4];
    float* y  = (float*)d_out;
    float2* ws2 = (float2*)d_ws;
    unsigned short* wpack  = (unsigned short*)((char*)d_ws + WS_WPACK_BYTE);
    unsigned short* ccpack = (unsigned short*)((char*)d_ws + WS_CCPACK_BYTE);
    char* busg = (char*)d_ws + WS_BUS_BYTE;

    k0_all<<<256, 512, 0, stream>>>(lp, bp, cp, delta, ws2, wpack, ccpack);

    if (ws_size >= WS_NEED) {
        // single-u-pass split path
        k3a_bus <<<NCHUNKS, 512, 0, stream>>>(u, ws2, wpack, busg);
        k2_carry<<<8, 256, 0, stream>>>(ws2);
        k3b_out <<<NCHUNKS, 512, 0, stream>>>(ws2, busg, ccpack, y);
    } else {
        // R4-proven fallback (u read twice)
        k1_end  <<<NCHUNKS, 512, 0, stream>>>(u, ws2, wpack);
        k2_carry<<<8, 256, 0, stream>>>(ws2);
        k3_main <<<NCHUNKS, 512, 0, stream>>>(u, ws2, wpack, ccpack, y);
    }
}

// Round 15
// 81.407 us; speedup vs baseline: 1.0702x; 1.0378x over previous
//
#include <hip/hip_runtime.h>
#include <hip/hip_bf16.h>

// Problem: B=16, T=8192, M=P=128, N2=128. Chunks: L=128, 64/batch, 1024 total.
// R15: split path. k3a = half-pipelined stage -> GEMM1 -> scale -> global bus + E
// (R14-proven). k3b = bus -> tri-cumsum in TWO t-halves (32 AGPR peak -> (512,6),
// 3 blocks/CU) -> x -> GEMM3 -> scattered y stores (R12-proven; the R13/R14
// y-LDS-transpose doubled bank conflicts and regressed). Fallback: R4 pair.
#define LCH 128
#define NCH 64
#define NCHUNKS 1024

typedef __attribute__((ext_vector_type(8))) short short8v;
typedef __attribute__((ext_vector_type(4))) short short4v;
typedef __attribute__((ext_vector_type(4))) float f32x4;

// ws layout: float2 region, packs, then bus.
#define W2_LDINV 0          // [128 r][128 n]  Ld^{-(r+1)}   (float2 idx)
#define W2_LDP   16384      // [128 r][128 n]  Ld^{r+1}
#define W2_E     32768      // [1024 g][128 n]
#define W2_CIN   163840     // [1024 g][128 n]
#define WS_WPACK_BYTE  2359296              // 32768 bf16: [ntile16][ks4][lane64][j8]
#define WS_CCPACK_BYTE (2359296 + 65536)    // 32768 bf16: [ptile8][ks8][lane64][j8]
#define WS_BUS_BYTE    (2359296 + 131072)   // 1024 chunks x 64 KB bf16 bus
#define WS_NEED ((size_t)WS_BUS_BYTE + (size_t)NCHUNKS * 65536)

// bus layout (LDS and global, byte-identical): byte(s,n') = (s>>3)*4096 + n'*16 + (s&7)*2
#define BUS_BYTE(s, np) ((((s) >> 3) * 4096) + ((np) * 16) + (((s) & 7) * 2))

__device__ inline unsigned short f2bf(float f) {
    union { __hip_bfloat16 h; unsigned short u; } v;
    v.h = __float2bfloat16(f);
    return v.u;
}
__device__ inline short4v pack4(float a, float b, float c, float d) {
    union { __hip_bfloat162 h2[2]; short4v s4; } pk;
    pk.h2[0] = __float22bfloat162_rn(make_float2(a, b));
    pk.h2[1] = __float22bfloat162_rn(make_float2(c, d));
    return pk.s4;
}

// ---------------- k0: all setup in one launch (256 blocks x 512) ----------------
__global__ void k0_all(const float* __restrict__ lp, const float* __restrict__ bp,
                       const float* __restrict__ cp, const float* __restrict__ delta,
                       float2* __restrict__ ws2, unsigned short* __restrict__ wpack,
                       unsigned short* __restrict__ ccpack) {
    const int r = blockIdx.x;
    const int tid = threadIdx.x;
    if (r < 128) {
        if (tid < 256) {
            const int n = tid & 127;
            const double d = (double)delta[0];
            const double lre = -exp((double)lp[n]);
            const double lim = (double)lp[128 + n];
            const double kk = (double)(r + 1) * d;
            if (tid < 128) {
                const double mag = exp(-lre * kk);
                ws2[W2_LDINV + r * 128 + n] = make_float2((float)(mag * cos(lim * kk)),
                                                          (float)(-mag * sin(lim * kk)));
            } else {
                const double mag = exp(lre * kk);
                ws2[W2_LDP + r * 128 + n] = make_float2((float)(mag * cos(lim * kk)),
                                                        (float)(mag * sin(lim * kk)));
            }
        }
    } else if (r < 192) {
        const int gid = (r - 128) * 512 + tid;         // 0..32767
        const int j = gid & 7;
        const int lane = (gid >> 3) & 63;
        const int ks = (gid >> 9) & 3;
        const int ntile = gid >> 11;
        const int np = ntile * 16 + (lane & 15);
        const int m = ks * 32 + ((lane >> 4) & 3) * 8 + j;
        const int n = np & 127;
        const double d = (double)delta[0];
        const double lre = -exp((double)lp[n]);
        const double lim = (double)lp[128 + n];
        const double er = exp(lre * d);
        const double ldr = er * cos(lim * d), ldi = er * sin(lim * d);
        const double nr = ldr - 1.0, ni = ldi;
        const double den = lre * lre + lim * lim;
        const double cr = (nr * lre + ni * lim) / den;
        const double ci = (ni * lre - nr * lim) / den;
        const double br = (double)bp[n * 128 + m];
        const double bi = (double)bp[16384 + n * 128 + m];
        const double v = (np < 128) ? (cr * br - ci * bi) : (cr * bi + ci * br);
        wpack[gid] = f2bf((float)v);
    } else {
        const int gid = (r - 192) * 512 + tid;         // 0..32767
        const int j = gid & 7;
        const int lane = (gid >> 3) & 63;
        const int ks = (gid >> 9) & 7;
        const int ptile = gid >> 12;
        const int p = ptile * 16 + (lane & 15);
        const int k = ks * 32 + ((lane >> 4) & 3) * 8 + j;
        const int n = k >> 1;
        const float v = ((k & 1) == 0) ? 2.0f * cp[p * 128 + n]
                                       : -2.0f * cp[16384 + p * 128 + n];
        ccpack[gid] = f2bf(v);
    }
}

// ---------------- shared helper: stage u chunk -> LDS bf16 [t][m], XOR swizzle ----------------
__device__ inline void stage_u(const float* __restrict__ uchunk, unsigned short* lds_u) {
    const float4* uf = (const float4*)uchunk;
    const int tid = threadIdx.x;
#pragma unroll
    for (int it = 0; it < 8; ++it) {
        const int f4 = it * 512 + tid;
        const float4 v = uf[f4];
        const int t = f4 >> 5;
        const int m = (f4 & 31) * 4;
        const int byte = (t * 256 + m * 2) ^ ((t & 7) << 4);
        *(short4v*)((char*)lds_u + byte) = pack4(v.x, v.y, v.z, v.w);
    }
}

// ================= k3a: half-pipelined stage -> GEMM1 -> scale -> global bus + E =================
// (R14-proven: 41.4 us.) Half h = u rows [64h, 64h+64). Bus is GLOBAL, so LDS halves
// are independent: stage h0; issue h1 loads; barrier; {GEMM1-h0 + scale + store} ||
// stage h1; barrier; GEMM1-h1 + scale + store + E.
__global__ __launch_bounds__(512, 4) void k3a_bus(const float* __restrict__ u,
                                                  float2* __restrict__ ws2,
                                                  const unsigned short* __restrict__ wpack,
                                                  char* __restrict__ busg) {
    __shared__ unsigned short lds_u[16384];   // 32 KB
    const int tid = threadIdx.x;
    const int lane = tid & 63;
    const int w = tid >> 6;
    const int tl = lane & 15;
    const int gq = (lane >> 4) & 3;
    const int g = blockIdx.x;
    const int b = g >> 6;
    const int c = g & 63;
    const int n = w * 16 + tl;
    const short8v* wp = (const short8v*)wpack;
    char* busc = busg + (size_t)g * 65536;
    const float4* uf = (const float4*)(u + (size_t)(b * 8192 + c * 128) * 128);

    // prefetch + stage half 0 (f4 idx 0..2047 -> rows 0..63)
    {
        float4 p0 = uf[tid], p1 = uf[512 + tid], p2 = uf[1024 + tid], p3 = uf[1536 + tid];
#pragma unroll
        for (int it = 0; it < 4; ++it) {
            const float4 v = (it == 0) ? p0 : (it == 1) ? p1 : (it == 2) ? p2 : p3;
            const int f4 = it * 512 + tid;
            const int t = f4 >> 5;
            const int m = (f4 & 31) * 4;
            const int byte = (t * 256 + m * 2) ^ ((t & 7) << 4);
            *(short4v*)((char*)lds_u + byte) = pack4(v.x, v.y, v.z, v.w);
        }
    }
    // issue half-1 loads; latency hides under GEMM1-h0 below
    float4 q0 = uf[2048 + tid], q1 = uf[2560 + tid], q2 = uf[3072 + tid], q3 = uf[3584 + tid];
    __builtin_amdgcn_sched_barrier(0);
    __syncthreads();                          // half 0 staged

    float er = 0.f, ei = 0.f;

    // ---- GEMM1-h0 + scale + bus store ----
    {
        f32x4 acc[4][2];
#pragma unroll
        for (int i = 0; i < 4; ++i) { acc[i][0] = (f32x4)0.f; acc[i][1] = (f32x4)0.f; }
        __builtin_amdgcn_s_setprio(1);
#pragma unroll
        for (int ks = 0; ks < 4; ++ks) {
            const short8v b0 = wp[(w * 4 + ks) * 64 + lane];
            const short8v b1 = wp[((8 + w) * 4 + ks) * 64 + lane];
#pragma unroll
            for (int tt2 = 0; tt2 < 4; ++tt2) {
                const int t = tt2 * 16 + tl;
                const int byte = (t * 256 + (ks * 32 + gq * 8) * 2) ^ ((t & 7) << 4);
                const short8v a = *(const short8v*)((const char*)lds_u + byte);
                acc[tt2][0] = __builtin_amdgcn_mfma_f32_16x16x32_bf16(a, b0, acc[tt2][0], 0, 0, 0);
                acc[tt2][1] = __builtin_amdgcn_mfma_f32_16x16x32_bf16(a, b1, acc[tt2][1], 0, 0, 0);
            }
        }
        __builtin_amdgcn_s_setprio(0);
#pragma unroll
        for (int tt2 = 0; tt2 < 4; ++tt2) {
            float vr[4], vi[4];
#pragma unroll
            for (int reg = 0; reg < 4; ++reg) {
                const int rr = tt2 * 16 + gq * 4 + reg;
                const float2 li = ws2[W2_LDINV + rr * 128 + n];
                const float br = acc[tt2][0][reg], bi = acc[tt2][1][reg];
                vr[reg] = li.x * br - li.y * bi;
                vi[reg] = li.x * bi + li.y * br;
                er += vr[reg];
                ei += vi[reg];
            }
            const int s0 = tt2 * 16 + gq * 4;
            const int rowr = w * 16 + tl;
            const int rowi = 128 + rowr;
            *(short4v*)(busc + BUS_BYTE(s0, rowr)) = pack4(vr[0], vr[1], vr[2], vr[3]);
            *(short4v*)(busc + BUS_BYTE(s0, rowi)) = pack4(vi[0], vi[1], vi[2], vi[3]);
        }
    }

    // stage half 1 (rows 64..127 — disjoint from h0 reads above; compiler interleaves)
    {
#pragma unroll
        for (int it = 0; it < 4; ++it) {
            const float4 v = (it == 0) ? q0 : (it == 1) ? q1 : (it == 2) ? q2 : q3;
            const int f4 = 2048 + it * 512 + tid;
            const int t = f4 >> 5;
            const int m = (f4 & 31) * 4;
            const int byte = (t * 256 + m * 2) ^ ((t & 7) << 4);
            *(short4v*)((char*)lds_u + byte) = pack4(v.x, v.y, v.z, v.w);
        }
    }
    __syncthreads();                          // half 1 staged

    // ---- GEMM1-h1 + scale + bus store + E ----
    {
        f32x4 acc[4][2];
#pragma unroll
        for (int i = 0; i < 4; ++i) { acc[i][0] = (f32x4)0.f; acc[i][1] = (f32x4)0.f; }
        __builtin_amdgcn_s_setprio(1);
#pragma unroll
        for (int ks = 0; ks < 4; ++ks) {
            const short8v b0 = wp[(w * 4 + ks) * 64 + lane];
            const short8v b1 = wp[((8 + w) * 4 + ks) * 64 + lane];
#pragma unroll
            for (int tt2 = 0; tt2 < 4; ++tt2) {
                const int t = (4 + tt2) * 16 + tl;
                const int byte = (t * 256 + (ks * 32 + gq * 8) * 2) ^ ((t & 7) << 4);
                const short8v a = *(const short8v*)((const char*)lds_u + byte);
                acc[tt2][0] = __builtin_amdgcn_mfma_f32_16x16x32_bf16(a, b0, acc[tt2][0], 0, 0, 0);
                acc[tt2][1] = __builtin_amdgcn_mfma_f32_16x16x32_bf16(a, b1, acc[tt2][1], 0, 0, 0);
            }
        }
        __builtin_amdgcn_s_setprio(0);
#pragma unroll
        for (int tt2 = 0; tt2 < 4; ++tt2) {
            float vr[4], vi[4];
#pragma unroll
            for (int reg = 0; reg < 4; ++reg) {
                const int rr = (4 + tt2) * 16 + gq * 4 + reg;
                const float2 li = ws2[W2_LDINV + rr * 128 + n];
                const float br = acc[tt2][0][reg], bi = acc[tt2][1][reg];
                vr[reg] = li.x * br - li.y * bi;
                vi[reg] = li.x * bi + li.y * br;
                er += vr[reg];
                ei += vi[reg];
            }
            const int s0 = (4 + tt2) * 16 + gq * 4;
            const int rowr = w * 16 + tl;
            const int rowi = 128 + rowr;
            *(short4v*)(busc + BUS_BYTE(s0, rowr)) = pack4(vr[0], vr[1], vr[2], vr[3]);
            *(short4v*)(busc + BUS_BYTE(s0, rowi)) = pack4(vi[0], vi[1], vi[2], vi[3]);
        }
    }

    // E[g][n] = Ld^128 * sum_s (Ldinv[s] (.) Bu[s,n])
    er += __shfl_xor(er, 16); ei += __shfl_xor(ei, 16);
    er += __shfl_xor(er, 32); ei += __shfl_xor(ei, 32);
    const float2 ld = ws2[W2_LDP + 127 * 128 + n];
    if (lane < 16) {
        ws2[W2_E + g * 128 + n] = make_float2(ld.x * er - ld.y * ei,
                                              ld.x * ei + ld.y * er);
    }
}

// ---------------- k2: chunk-level scan -> carry-in ----------------
__global__ void k2_carry(float2* __restrict__ ws2) {
    const int idx = blockIdx.x * 256 + threadIdx.x;   // 0..2047
    const int b = idx >> 7;
    const int n = idx & 127;
    const float2 l = ws2[W2_LDP + 127 * 128 + n];
    float cr = 0.f, ci = 0.f;
    for (int c = 0; c < NCH; ++c) {
        const int o = (b * NCH + c) * 128 + n;
        ws2[W2_CIN + o] = make_float2(cr, ci);
        const float2 e = ws2[W2_E + o];
        const float nr = fmaf(l.x, cr, fmaf(-l.y, ci, e.x));
        const float ni = fmaf(l.x, ci, fmaf(l.y, cr, e.y));
        cr = nr; ci = ni;
    }
}

// ================= k3b: bus frags -> tri-cumsum (two t-halves, 32 AGPR peak) ->
// x -> GEMM3 -> scattered y. (512,6): 3 blocks/CU. =================
__global__ __launch_bounds__(512, 6) void k3b_out(const float2* __restrict__ ws2,
                                                  const char* __restrict__ busg,
                                                  const unsigned short* __restrict__ ccpack,
                                                  float* __restrict__ y) {
    __shared__ unsigned short lds[32768];     // 64 KB: x tile [128 t][256 k''] bf16
    const int tid = threadIdx.x;
    const int lane = tid & 63;
    const int w = tid >> 6;
    const int tl = lane & 15;
    const int gq = (lane >> 4) & 3;
    const int g = blockIdx.x;
    const int b = g >> 6;
    const int c = g & 63;
    const int n = w * 16 + tl;
    const short8v* cc8 = (const short8v*)ccpack;
    const char* busc = busg + (size_t)g * 65536;

    short8v ONES, D0, D1;
#pragma unroll
    for (int j = 0; j < 8; ++j) {
        const int sl = gq * 8 + j;
        ONES[j] = (short)0x3F80;
        D0[j] = (sl <= tl) ? (short)0x3F80 : (short)0;
        D1[j] = (sl <= tl + 16) ? (short)0x3F80 : (short)0;
    }
    const float2 cin = ws2[W2_CIN + g * 128 + n];
    const int rowr = w * 16 + tl;
    const int rowi = 128 + rowr;

    // ---- half A: z rows 0..63 need only ks 0..1 ----
    {
        f32x4 z[4][2];
#pragma unroll
        for (int i = 0; i < 4; ++i) { z[i][0] = (f32x4)0.f; z[i][1] = (f32x4)0.f; }
        __builtin_amdgcn_s_setprio(1);
#pragma unroll
        for (int ks = 0; ks < 2; ++ks) {
            const int sb = ks * 32 + gq * 8;
            const short8v b0 = *(const short8v*)(busc + BUS_BYTE(sb, rowr));
            const short8v b1 = *(const short8v*)(busc + BUS_BYTE(sb, rowi));
#pragma unroll
            for (int tt = 0; tt < 4; ++tt) {
                if (tt < 2 * ks) continue;                   // zero block
                const short8v a = (tt == 2 * ks) ? D0 : ((tt == 2 * ks + 1) ? D1 : ONES);
                z[tt][0] = __builtin_amdgcn_mfma_f32_16x16x32_bf16(a, b0, z[tt][0], 0, 0, 0);
                z[tt][1] = __builtin_amdgcn_mfma_f32_16x16x32_bf16(a, b1, z[tt][1], 0, 0, 0);
            }
        }
        __builtin_amdgcn_s_setprio(0);
#pragma unroll
        for (int tt = 0; tt < 4; ++tt) {
#pragma unroll
            for (int reg = 0; reg < 4; ++reg) {
                const int r = tt * 16 + gq * 4 + reg;
                const float2 ld = ws2[W2_LDP + r * 128 + n];
                const float zr = z[tt][0][reg] + cin.x;
                const float zi = z[tt][1][reg] + cin.y;
                const float xr = ld.x * zr - ld.y * zi;
                const float xi = ld.x * zi + ld.y * zr;
                union { __hip_bfloat162 h2; unsigned uu; } pk;
                pk.h2 = __float22bfloat162_rn(make_float2(xr, xi));
                const int byte = (r * 512 + n * 4) ^ ((r & 7) << 4);
                *(unsigned*)((char*)lds + byte) = pk.uu;
            }
        }
    }

    // ---- half B: z rows 64..127 need ks 0..3 ----
    {
        f32x4 z[4][2];
#pragma unroll
        for (int i = 0; i < 4; ++i) { z[i][0] = (f32x4)0.f; z[i][1] = (f32x4)0.f; }
        __builtin_amdgcn_s_setprio(1);
#pragma unroll
        for (int ks = 0; ks < 4; ++ks) {
            const int sb = ks * 32 + gq * 8;
            const short8v b0 = *(const short8v*)(busc + BUS_BYTE(sb, rowr));
            const short8v b1 = *(const short8v*)(busc + BUS_BYTE(sb, rowi));
#pragma unroll
            for (int tt2 = 0; tt2 < 4; ++tt2) {
                const int tt = 4 + tt2;
                if (tt < 2 * ks) continue;                   // zero block (ks=3, tt2<2)
                const short8v a = (tt == 2 * ks) ? D0 : ((tt == 2 * ks + 1) ? D1 : ONES);
                z[tt2][0] = __builtin_amdgcn_mfma_f32_16x16x32_bf16(a, b0, z[tt2][0], 0, 0, 0);
                z[tt2][1] = __builtin_amdgcn_mfma_f32_16x16x32_bf16(a, b1, z[tt2][1], 0, 0, 0);
            }
        }
        __builtin_amdgcn_s_setprio(0);
#pragma unroll
        for (int tt2 = 0; tt2 < 4; ++tt2) {
#pragma unroll
            for (int reg = 0; reg < 4; ++reg) {
                const int r = (4 + tt2) * 16 + gq * 4 + reg;
                const float2 ld = ws2[W2_LDP + r * 128 + n];
                const float zr = z[tt2][0][reg] + cin.x;
                const float zi = z[tt2][1][reg] + cin.y;
                const float xr = ld.x * zr - ld.y * zi;
                const float xi = ld.x * zi + ld.y * zr;
                union { __hip_bfloat162 h2; unsigned uu; } pk;
                pk.h2 = __float22bfloat162_rn(make_float2(xr, xi));
                const int byte = (r * 512 + n * 4) ^ ((r & 7) << 4);
                *(unsigned*)((char*)lds + byte) = pk.uu;
            }
        }
    }
    __syncthreads();

    // GEMM3: y[t][p]; wave w owns p-tile w, all t
    f32x4 yac[8];
#pragma unroll
    for (int i = 0; i < 8; ++i) yac[i] = (f32x4)0.f;
    __builtin_amdgcn_s_setprio(1);
#pragma unroll
    for (int ks = 0; ks < 8; ++ks) {
        const short8v bfrg = cc8[(w * 8 + ks) * 64 + lane];
#pragma unroll
        for (int tt = 0; tt < 8; ++tt) {
            const int t = tt * 16 + tl;
            const int byte = (t * 512 + (ks * 32 + gq * 8) * 2) ^ ((t & 7) << 4);
            const short8v a = *(const short8v*)((const char*)lds + byte);
            yac[tt] = __builtin_amdgcn_mfma_f32_16x16x32_bf16(a, bfrg, yac[tt], 0, 0, 0);
        }
    }
    __builtin_amdgcn_s_setprio(0);
    const int p = w * 16 + tl;
    float* yrow = y + (size_t)(b * 8192 + c * 128) * 128;
#pragma unroll
    for (int tt = 0; tt < 8; ++tt) {
#pragma unroll
        for (int reg = 0; reg < 4; ++reg) {
            const int t = tt * 16 + gq * 4 + reg;
            yrow[t * 128 + p] = yac[tt][reg];
        }
    }
}

// ================= fallback path: R4-proven k1 + k3 (used if ws too small) =================
__global__ __launch_bounds__(512, 4) void k1_end(const float* __restrict__ u,
                                                 float2* __restrict__ ws2,
                                                 const unsigned short* __restrict__ wpack) {
    __shared__ unsigned short lds_u[16384];   // 32 KB
    const int tid = threadIdx.x;
    const int lane = tid & 63;
    const int w = tid >> 6;
    const int tl = lane & 15;
    const int gq = (lane >> 4) & 3;
    const int g = blockIdx.x;
    const int b = g >> 6;
    const int c = g & 63;
    const int n = w * 16 + tl;
    stage_u(u + (size_t)(b * 8192 + c * 128) * 128, lds_u);
    __syncthreads();
    const short8v* wp = (const short8v*)wpack;
    float er = 0.f, ei = 0.f;
#pragma unroll
    for (int h = 0; h < 2; ++h) {
        f32x4 acc[4][2];
#pragma unroll
        for (int i = 0; i < 4; ++i) { acc[i][0] = (f32x4)0.f; acc[i][1] = (f32x4)0.f; }
        __builtin_amdgcn_s_setprio(1);
#pragma unroll
        for (int ks = 0; ks < 4; ++ks) {
            const short8v b0 = wp[(w * 4 + ks) * 64 + lane];
            const short8v b1 = wp[((8 + w) * 4 + ks) * 64 + lane];
#pragma unroll
            for (int tt2 = 0; tt2 < 4; ++tt2) {
                const int t = (h * 4 + tt2) * 16 + tl;
                const int byte = (t * 256 + (ks * 32 + gq * 8) * 2) ^ ((t & 7) << 4);
                const short8v a = *(const short8v*)((const char*)lds_u + byte);
                acc[tt2][0] = __builtin_amdgcn_mfma_f32_16x16x32_bf16(a, b0, acc[tt2][0], 0, 0, 0);
                acc[tt2][1] = __builtin_amdgcn_mfma_f32_16x16x32_bf16(a, b1, acc[tt2][1], 0, 0, 0);
            }
        }
        __builtin_amdgcn_s_setprio(0);
        __builtin_amdgcn_sched_barrier(0);
#pragma unroll
        for (int tt2 = 0; tt2 < 4; ++tt2) {
#pragma unroll
            for (int reg = 0; reg < 4; ++reg) {
                const int r = (h * 4 + tt2) * 16 + gq * 4 + reg;
                const float2 li = ws2[W2_LDINV + r * 128 + n];
                const float br = acc[tt2][0][reg], bi = acc[tt2][1][reg];
                er += li.x * br - li.y * bi;
                ei += li.x * bi + li.y * br;
            }
        }
        __builtin_amdgcn_sched_barrier(0);
    }
    er += __shfl_xor(er, 16); ei += __shfl_xor(ei, 16);
    er += __shfl_xor(er, 32); ei += __shfl_xor(ei, 32);
    const float2 ld = ws2[W2_LDP + 127 * 128 + n];
    if (lane < 16) {
        ws2[W2_E + g * 128 + n] = make_float2(ld.x * er - ld.y * ei,
                                              ld.x * ei + ld.y * er);
    }
}

__global__ __launch_bounds__(512, 4) void k3_main(const float* __restrict__ u,
                                                  const float2* __restrict__ ws2,
                                                  const unsigned short* __restrict__ wpack,
                                                  const unsigned short* __restrict__ ccpack,
                                                  float* __restrict__ y) {
    __shared__ unsigned short lds[32768];     // 64 KB
    const int tid = threadIdx.x;
    const int lane = tid & 63;
    const int w = tid >> 6;
    const int tl = lane & 15;
    const int gq = (lane >> 4) & 3;
    const int g = blockIdx.x;
    const int b = g >> 6;
    const int c = g & 63;
    const int n = w * 16 + tl;
    const short8v* wp = (const short8v*)wpack;
    const short8v* cc8 = (const short8v*)ccpack;

    stage_u(u + (size_t)(b * 8192 + c * 128) * 128, lds);
    __syncthreads();
#pragma unroll
    for (int hh = 0; hh < 2; ++hh) {
        const int h = 1 - hh;
        f32x4 acc[4][2];
#pragma unroll
        for (int i = 0; i < 4; ++i) { acc[i][0] = (f32x4)0.f; acc[i][1] = (f32x4)0.f; }
        __builtin_amdgcn_s_setprio(1);
#pragma unroll
        for (int ks = 0; ks < 4; ++ks) {
            const short8v b0 = wp[(w * 4 + ks) * 64 + lane];
            const short8v b1 = wp[((8 + w) * 4 + ks) * 64 + lane];
#pragma unroll
            for (int tt2 = 0; tt2 < 4; ++tt2) {
                const int t = (h * 4 + tt2) * 16 + tl;
                const int byte = (t * 256 + (ks * 32 + gq * 8) * 2) ^ ((t & 7) << 4);
                const short8v a = *(const short8v*)((const char*)lds + byte);
                acc[tt2][0] = __builtin_amdgcn_mfma_f32_16x16x32_bf16(a, b0, acc[tt2][0], 0, 0, 0);
                acc[tt2][1] = __builtin_amdgcn_mfma_f32_16x16x32_bf16(a, b1, acc[tt2][1], 0, 0, 0);
            }
        }
        __builtin_amdgcn_s_setprio(0);
        __builtin_amdgcn_sched_barrier(0);
        if (h == 0) __syncthreads();
#pragma unroll
        for (int tt2 = 0; tt2 < 4; ++tt2) {
            float vr[4], vi[4];
#pragma unroll
            for (int reg = 0; reg < 4; ++reg) {
                const int r = (h * 4 + tt2) * 16 + gq * 4 + reg;
                const float2 li = ws2[W2_LDINV + r * 128 + n];
                const float br = acc[tt2][0][reg], bi = acc[tt2][1][reg];
                vr[reg] = li.x * br - li.y * bi;
                vi[reg] = li.x * bi + li.y * br;
            }
            const int s0 = (h * 4 + tt2) * 16 + gq * 4;
            const int rowr = w * 16 + tl;
            const int rowi = 128 + rowr;
            *(short4v*)((char*)lds + BUS_BYTE(s0, rowr)) = pack4(vr[0], vr[1], vr[2], vr[3]);
            *(short4v*)((char*)lds + BUS_BYTE(s0, rowi)) = pack4(vi[0], vi[1], vi[2], vi[3]);
        }
        __builtin_amdgcn_sched_barrier(0);
    }
    short8v ONES, D0, D1;
#pragma unroll
    for (int j = 0; j < 8; ++j) {
        const int sl = gq * 8 + j;
        ONES[j] = (short)0x3F80;
        D0[j] = (sl <= tl) ? (short)0x3F80 : (short)0;
        D1[j] = (sl <= tl + 16) ? (short)0x3F80 : (short)0;
    }
    f32x4 z[8][2];
#pragma unroll
    for (int i = 0; i < 8; ++i) { z[i][0] = (f32x4)0.f; z[i][1] = (f32x4)0.f; }
#pragma unroll
    for (int ks = 0; ks < 4; ++ks) {
        const int sb = ks * 32 + gq * 8;
        const int rowr = w * 16 + tl;
        const int rowi = 128 + rowr;
        const short8v b0 = *(const short8v*)((const char*)lds + BUS_BYTE(sb, rowr));
        const short8v b1 = *(const short8v*)((const char*)lds + BUS_BYTE(sb, rowi));
#pragma unroll
        for (int tt = 0; tt < 8; ++tt) {
            if (tt < 2 * ks) continue;
            const short8v a = (tt == 2 * ks) ? D0 : ((tt == 2 * ks + 1) ? D1 : ONES);
            z[tt][0] = __builtin_amdgcn_mfma_f32_16x16x32_bf16(a, b0, z[tt][0], 0, 0, 0);
            z[tt][1] = __builtin_amdgcn_mfma_f32_16x16x32_bf16(a, b1, z[tt][1], 0, 0, 0);
        }
    }
    __syncthreads();
    const float2 cin = ws2[W2_CIN + g * 128 + n];
#pragma unroll
    for (int tt = 0; tt < 8; ++tt) {
#pragma unroll
        for (int reg = 0; reg < 4; ++reg) {
            const int r = tt * 16 + gq * 4 + reg;
            const float2 ld = ws2[W2_LDP + r * 128 + n];
            const float zr = z[tt][0][reg] + cin.x;
            const float zi = z[tt][1][reg] + cin.y;
            const float xr = ld.x * zr - ld.y * zi;
            const float xi = ld.x * zi + ld.y * zr;
            union { __hip_bfloat162 h2; unsigned uu; } pk;
            pk.h2 = __float22bfloat162_rn(make_float2(xr, xi));
            const int byte = (r * 512 + n * 4) ^ ((r & 7) << 4);
            *(unsigned*)((char*)lds + byte) = pk.uu;
        }
    }
    __syncthreads();
    f32x4 yac[8];
#pragma unroll
    for (int i = 0; i < 8; ++i) yac[i] = (f32x4)0.f;
    __builtin_amdgcn_s_setprio(1);
#pragma unroll
    for (int ks = 0; ks < 8; ++ks) {
        const short8v bfrg = cc8[(w * 8 + ks) * 64 + lane];
#pragma unroll
        for (int tt = 0; tt < 8; ++tt) {
            const int t = tt * 16 + tl;
            const int byte = (t * 512 + (ks * 32 + gq * 8) * 2) ^ ((t & 7) << 4);
            const short8v a = *(const short8v*)((const char*)lds + byte);
            yac[tt] = __builtin_amdgcn_mfma_f32_16x16x32_bf16(a, bfrg, yac[tt], 0, 0, 0);
        }
    }
    __builtin_amdgcn_s_setprio(0);
    const int p = w * 16 + tl;
    float* yrow = y + (size_t)(b * 8192 + c * 128) * 128;
#pragma unroll
    for (int tt = 0; tt < 8; ++tt) {
#pragma unroll
        for (int reg = 0; reg < 4; ++reg) {
            const int t = tt * 16 + gq * 4 + reg;
            yrow[t * 128 + p] = yac[tt][reg];
        }
    }
}

extern "C" void kernel_launch(void* const* d_in, const int* in_sizes, int n_in,
                              void* d_out, int out_size, void* d_ws, size_t ws_size,
                              hipStream_t stream) {
    const float* u     = (const float*)d_in[0];
    const float* lp    = (const float*)d_in[1];
    const float* bp    = (const float*)d_in[2];
    const float* cp    = (const float*)d_in[3];
    const float* delta = (const float*)d_in[4];
    float* y  = (float*)d_out;
    float2* ws2 = (float2*)d_ws;
    unsigned short* wpack  = (unsigned short*)((char*)d_ws + WS_WPACK_BYTE);
    unsigned short* ccpack = (unsigned short*)((char*)d_ws + WS_CCPACK_BYTE);
    char* busg = (char*)d_ws + WS_BUS_BYTE;

    k0_all<<<256, 512, 0, stream>>>(lp, bp, cp, delta, ws2, wpack, ccpack);

    if (ws_size >= WS_NEED) {
        // single-u-pass split path
        k3a_bus <<<NCHUNKS, 512, 0, stream>>>(u, ws2, wpack, busg);
        k2_carry<<<8, 256, 0, stream>>>(ws2);
        k3b_out <<<NCHUNKS, 512, 0, stream>>>(ws2, busg, ccpack, y);
    } else {
        // R4-proven fallback (u read twice)
        k1_end  <<<NCHUNKS, 512, 0, stream>>>(u, ws2, wpack);
        k2_carry<<<8, 256, 0, stream>>>(ws2);
        k3_main <<<NCHUNKS, 512, 0, stream>>>(u, ws2, wpack, ccpack, y);
    }
}